// Round 9
// baseline (218.429 us; speedup 1.0000x reference)
//
#include <hip/hip_runtime.h>
#include <math.h>
#include <stdint.h>

#define Ww 22
#define P_ 484            // H*W (also number of filters)
#define S_ 16
#define C_ 256
#define TSZ 1849          // 43*43 distance table

typedef _Float16 f16x8 __attribute__((ext_vector_type(8)));
typedef _Float16 f16x4 __attribute__((ext_vector_type(4)));
typedef float f32x4 __attribute__((ext_vector_type(4)));

// XCD-chunked remap: grid size n divisible by 8; XCD x (= bid%8) gets wgids
// [x*n/8,(x+1)*n/8) -> each XCD owns the SAME 2 s-slices in every kernel.
__device__ __forceinline__ int xcd_chunk(int bid, int chunk) {
    return (bid & 7) * chunk + (bid >> 3);
}

// ---- global_load_lds width-16: LDS dest is wave-uniform base + lane*16B ----
__device__ __forceinline__ void gld16(const _Float16* g, _Float16* lds) {
    auto* lp = (__attribute__((address_space(3))) uint32_t*)(uintptr_t)(lds);
    auto* gp = (const __attribute__((address_space(1))) uint32_t*)(uintptr_t)(g);
    __builtin_amdgcn_global_load_lds(gp, lp, 16, 0, 0);
}

__device__ __forceinline__ f32x4 map_entry(const float* label_w, const float* mask_w,
                                           const float* spatial_w, float d) {
    float lab = 0.f, msk = 0.f, spw = 0.f;
#pragma unroll
    for (int b = 0; b < 9; ++b) {
        float wb = fmaxf(0.f, 1.f - fabsf(d - (float)b));
        lab += wb * label_w[b];
        msk += wb * mask_w[b];
        spw += wb * spatial_w[b];
    }
    float w9 = fminf(fmaxf(1.f + (d - 9.f), 0.f), 1.f);
    lab += w9 * label_w[9];
    msk += w9 * mask_w[9];
    spw += w9 * spatial_w[9];
    f32x4 o;
    o[0] = lab;
    o[1] = 1.f / (1.f + expf(-msk));
    o[2] = spw * spw;
    o[3] = spw;
    return o;
}

// ---------------- merged prologue: maps + winit + trans ---------------------
__global__ __launch_bounds__(256) void k_pro(
    const float* __restrict__ filt, const float* __restrict__ feat,
    const float* __restrict__ lw, const float* __restrict__ mw,
    const float* __restrict__ sw,
    float* __restrict__ Wf, _Float16* __restrict__ Wh,
    _Float16* __restrict__ f2h, _Float16* __restrict__ f2th,
    f32x4* __restrict__ map4t) {
    int wgid = xcd_chunk(blockIdx.x, 514);
    int x = wgid / 514;
    int local = wgid % 514;
    int t = threadIdx.x;
    if (local == 0) {
        int idx = x + 8 * t;
        if (idx < TSZ) {
            int dx = idx / 43 - 21, dy = idx % 43 - 21;
            float d = sqrtf((float)(dx * dx + dy * dy)) * 2.0f;
            map4t[idx] = map_entry(lw, mw, sw, d);
        }
    } else if (local < 257) {
        int u = local - 1;
        int s = x * 2 + (u >> 7);
        int f = (u & 127) * 4 + (t >> 6);
        int c = (t & 63) * 4;
        size_t oh = ((size_t)(s * 512 + f)) * C_ + c;
        if (f < P_) {
            size_t o = ((size_t)(s * P_ + f)) * C_ + c;
            f32x4 v = *(const f32x4*)(filt + o);
            *(f32x4*)(Wf + o) = v;
            f16x4 h;
#pragma unroll
            for (int q = 0; q < 4; ++q) h[q] = (_Float16)v[q];
            *(f16x4*)(Wh + oh) = h;
        } else {
            f16x4 h = {};
            *(f16x4*)(Wh + oh) = h;   // zero pad rows
        }
    } else if (local < 513) {
        int u = local - 257;
        int s = x * 2 + (u >> 7);
        int rem = u & 127;
        int p0 = (rem & 15) * 32, c0 = (rem >> 4) * 32;
        int cc = t & 31, rr = t >> 5;
        __shared__ float tb[32][33];
#pragma unroll
        for (int q = 0; q < 4; ++q) {
            int c = c0 + rr + q * 8;
            int p = p0 + cc;
            float v = (p < P_) ? feat[((size_t)s * C_ + c) * P_ + p] : 0.f;
            f2h[((size_t)s * C_ + c) * 512 + p] = (_Float16)v;
            tb[rr + q * 8][cc] = v;
        }
        __syncthreads();
#pragma unroll
        for (int q = 0; q < 4; ++q) {
            int p = p0 + rr + q * 8;   // rows >= 484 hold zeros
            f2th[((size_t)s * 512 + p) * C_ + c0 + cc] = (_Float16)tb[cc][rr + q * 8];
        }
    }
}

// ---------------- GEMM1: scores = W . f2^T -> scoresh + residh --------------
// proven 64x64-tile / BK=128 single-buffer loop (round-6 structure)
__global__ __launch_bounds__(256, 4) void k_g1(
    const _Float16* __restrict__ Ah, const _Float16* __restrict__ Bh,
    const f32x4* __restrict__ map4t,
    _Float16* __restrict__ residh, _Float16* __restrict__ scoresh) {
    int tid = threadIdx.x;
    int w = tid >> 6, l = tid & 63;
    int wgid = xcd_chunk(blockIdx.x, 128);   // 1024 blocks
    int s = wgid / 64;
    int rem = wgid % 64;
    int m0 = (rem / 8) * 64, n0 = (rem % 8) * 64;
    int wm = w >> 1, wn = w & 1;
    int r16 = l & 15;

    __shared__ _Float16 As[64 * 128];
    __shared__ _Float16 Bs[64 * 128];

    int lrow = w * 4 + (l >> 4);
    int gsrc = ((l & 15) ^ lrow) << 3;
    const _Float16* gA = Ah + (size_t)s * 131072 + (size_t)(m0 + lrow) * 256 + gsrc;
    const _Float16* gB = Bh + (size_t)s * 131072 + (size_t)(n0 + lrow) * 256 + gsrc;

    f32x4 acc[2][2] = {};

#pragma unroll
    for (int t = 0; t < 2; ++t) {
#pragma unroll
        for (int i = 0; i < 4; ++i) {
            gld16(gA + (size_t)i * 16 * 256 + t * 128, &As[(i * 16 + w * 4) * 128]);
            gld16(gB + (size_t)i * 16 * 256 + t * 128, &Bs[(i * 16 + w * 4) * 128]);
        }
        __syncthreads();
#pragma unroll
        for (int kk = 0; kk < 4; ++kk) {
            int px = ((kk * 4 + (l >> 4)) ^ r16) << 3;
            f16x8 af[2], bf[2];
#pragma unroll
            for (int ti = 0; ti < 2; ++ti)
                af[ti] = *(const f16x8*)&As[(wm * 32 + ti * 16 + r16) * 128 + px];
#pragma unroll
            for (int tj = 0; tj < 2; ++tj)
                bf[tj] = *(const f16x8*)&Bs[(wn * 32 + tj * 16 + r16) * 128 + px];
#pragma unroll
            for (int ti = 0; ti < 2; ++ti)
#pragma unroll
                for (int tj = 0; tj < 2; ++tj)
                    acc[ti][tj] = __builtin_amdgcn_mfma_f32_16x16x32_f16(
                        af[ti], bf[tj], acc[ti][tj], 0, 0, 0);
        }
        if (t == 0) __syncthreads();
    }

    int q4 = (l >> 4) * 4;
#pragma unroll
    for (int ti = 0; ti < 2; ++ti)
#pragma unroll
        for (int r = 0; r < 4; ++r) {
            int m = m0 + wm * 32 + ti * 16 + q4 + r;
            int im = m / 22, jm = m - im * 22;
#pragma unroll
            for (int tj = 0; tj < 2; ++tj) {
                int n = n0 + wn * 32 + tj * 16 + r16;
                float sc = acc[ti][tj][r];   // pads -> 0 (zero operands)
                float res = 0.f;
                size_t po = ((size_t)(s * 512 + m)) * 512 + n;
                if (m < P_ && n < P_) {
                    int kn = n / 22, ln = n - kn * 22;
                    f32x4 m4 = map4t[(kn - im + 21) * 43 + (ln - jm + 21)];
                    float sgn = (sc > 0.f) ? 1.f : ((sc < 0.f) ? -1.f : 0.f);
                    float msk = 0.5f * (1.f - m4[1]) * sgn + 0.5f * (1.f + m4[1]);
                    res = msk * (m4[2] * (msk * sc - m4[0]));
                }
                residh[po] = (_Float16)res;
                scoresh[po] = (_Float16)sc;
            }
        }
}

// ---------------- fused iteration kernel ------------------------------------
// Block owns (s, 32 f-rows). Phases:
//   A: wgrad rows = resid . f2h^T + reg*Wh  (K=512) -> Wg LDS + num partials
//   B: sgraw rows = Wg . f2th^T             (K=256) -> Sg LDS + den partials
//   C: alpha -> W update (+ scores recurrence + residual epilogue if !LAST)
// grid 256 (16 s x 16 fblk), XCD chunk 32 -> 2 s per XCD (chain-aligned).
template <bool LAST>
__global__ __launch_bounds__(256, 1) void k_iter(
    _Float16* __restrict__ residh, _Float16* __restrict__ scoresh,
    const _Float16* __restrict__ f2h, const _Float16* __restrict__ f2th,
    _Float16* __restrict__ Wh, float* __restrict__ Wf,
    const f32x4* __restrict__ map4t,
    const float* __restrict__ freg, const float* __restrict__ lsl) {

    __shared__ _Float16 Bs[128 * 128];    // 32 KB staging (shared by A/B phases)
    __shared__ _Float16 Afull[32 * 512];  // 32 KB resid rows (swizzled)
    __shared__ _Float16 Wg[32 * 256];     // 16 KB wgrad rows (swizzled)
    __shared__ _Float16 Sg[32 * 512];     // 32 KB sgraw rows (linear)
    __shared__ float num_p[2][32], den_p[2][32], alpha_l[32];

    int tid = threadIdx.x;
    int w = tid >> 6, l = tid & 63;
    int wgid = xcd_chunk(blockIdx.x, 32);
    int s = wgid >> 4;
    int m0 = (wgid & 15) * 32;
    int wm = w >> 1, wn = w & 1;
    int r16 = l & 15;
    int g4 = l >> 4;
    int q4 = g4 * 4;

    float fr = freg[0];
    float regw = fmaxf(fr * fr, 1e-10f);
    float step = expf(lsl[0]);

    if (tid < 64) { ((float*)num_p)[tid] = 0.f; ((float*)den_p)[tid] = 0.f; }
    {   // stage Afull = residh rows [m0..m0+32) x 512 (1 row per wave-issue)
        const _Float16* src = residh + ((size_t)(s * 512 + m0)) * 512;
#pragma unroll
        for (int i = 0; i < 8; ++i) {
            int row = w * 8 + i;
            gld16(src + (size_t)row * 512 + ((l ^ (row & 15)) << 3), Afull + row * 512);
        }
    }
    __syncthreads();

    // ---------------- phase A: wgrad (32 x 256, K=512) ----------------
#pragma unroll
    for (int nn = 0; nn < 2; ++nn) {
        f32x4 acc[4];
#pragma unroll
        for (int tj = 0; tj < 4; ++tj) acc[tj] = (f32x4){0.f, 0.f, 0.f, 0.f};
#pragma unroll
        for (int t = 0; t < 4; ++t) {
            const _Float16* src = f2h + (size_t)s * 131072 + (size_t)(nn * 128) * 512 + t * 128;
#pragma unroll
            for (int i = 0; i < 8; ++i) {
                int lr = w * 32 + i * 4 + g4;
                gld16(src + (size_t)lr * 512 + (((l & 15) ^ (lr & 15)) << 3),
                      Bs + (w * 32 + i * 4) * 128);
            }
            __syncthreads();
#pragma unroll
            for (int kk = 0; kk < 4; ++kk) {
                int pg = ((kk * 4 + g4) ^ r16) << 3;
                f16x8 af = *(const f16x8*)&Afull[(wm * 16 + r16) * 512 + t * 128 + pg];
                f16x8 bf[4];
#pragma unroll
                for (int tj = 0; tj < 4; ++tj)
                    bf[tj] = *(const f16x8*)&Bs[(wn * 64 + tj * 16 + r16) * 128 + pg];
#pragma unroll
                for (int tj = 0; tj < 4; ++tj)
                    acc[tj] = __builtin_amdgcn_mfma_f32_16x16x32_f16(af, bf[tj], acc[tj], 0, 0, 0);
            }
            __syncthreads();
        }
        // epilogue A: Wg <- acc + reg*Wh; num partials
#pragma unroll
        for (int r = 0; r < 4; ++r) {
            int m_l = wm * 16 + q4 + r;
            float v = 0.f;
#pragma unroll
            for (int tj = 0; tj < 4; ++tj) {
                int c = nn * 128 + wn * 64 + tj * 16 + r16;
                float wg = acc[tj][r] + regw * (float)Wh[((size_t)(s * 512 + m0 + m_l)) * 256 + c];
                Wg[m_l * 256 + (((c >> 3) ^ (m_l & 15)) << 3) + (c & 7)] = (_Float16)wg;
                v += wg * wg;
            }
            v += __shfl_xor(v, 1); v += __shfl_xor(v, 2);
            v += __shfl_xor(v, 4); v += __shfl_xor(v, 8);
            if (r16 == 0) num_p[wn][m_l] += v;
        }
    }

    // ---------------- phase B: sgraw (32 x 484, K=256) ----------------
#pragma unroll
    for (int nn2 = 0; nn2 < 4; ++nn2) {
        f32x4 acc[4];
#pragma unroll
        for (int tj = 0; tj < 4; ++tj) acc[tj] = (f32x4){0.f, 0.f, 0.f, 0.f};
#pragma unroll
        for (int t2 = 0; t2 < 2; ++t2) {
            const _Float16* src = f2th + (size_t)s * 131072 + (size_t)(nn2 * 128) * 256 + t2 * 128;
#pragma unroll
            for (int i = 0; i < 8; ++i) {
                int lr = w * 32 + i * 4 + g4;
                gld16(src + (size_t)lr * 256 + (((l & 15) ^ (lr & 15)) << 3),
                      Bs + (w * 32 + i * 4) * 128);
            }
            __syncthreads();
#pragma unroll
            for (int kk = 0; kk < 4; ++kk) {
                int pg = ((kk * 4 + g4) ^ r16) << 3;
                f16x8 af = *(const f16x8*)&Wg[(wm * 16 + r16) * 256 + t2 * 128 + pg];
                f16x8 bf[4];
#pragma unroll
                for (int tj = 0; tj < 4; ++tj)
                    bf[tj] = *(const f16x8*)&Bs[(wn * 64 + tj * 16 + r16) * 128 + pg];
#pragma unroll
                for (int tj = 0; tj < 4; ++tj)
                    acc[tj] = __builtin_amdgcn_mfma_f32_16x16x32_f16(af, bf[tj], acc[tj], 0, 0, 0);
            }
            __syncthreads();
        }
        // epilogue B: Sg store + den partials (mask recomputed from scoresh)
#pragma unroll
        for (int r = 0; r < 4; ++r) {
            int m_l = wm * 16 + q4 + r;
            int mg = m0 + m_l;
            int im = mg / 22, jm = mg - im * 22;
            float v = 0.f;
#pragma unroll
            for (int tj = 0; tj < 4; ++tj) {
                int n = nn2 * 128 + wn * 64 + tj * 16 + r16;
                float a = acc[tj][r];
                if (!LAST) Sg[m_l * 512 + n] = (_Float16)a;
                if (mg < P_ && n < P_) {
                    float sc = (float)scoresh[((size_t)(s * 512 + mg)) * 512 + n];
                    int kn = n / 22, ln = n - kn * 22;
                    f32x4 m4 = map4t[(kn - im + 21) * 43 + (ln - jm + 21)];
                    float sgn = (sc > 0.f) ? 1.f : ((sc < 0.f) ? -1.f : 0.f);
                    float msk = 0.5f * (1.f - m4[1]) * sgn + 0.5f * (1.f + m4[1]);
                    float sg = m4[3] * msk * a;
                    v += sg * sg;
                }
            }
            v += __shfl_xor(v, 1); v += __shfl_xor(v, 2);
            v += __shfl_xor(v, 4); v += __shfl_xor(v, 8);
            if (r16 == 0) den_p[wn][m_l] += v;
        }
    }
    __syncthreads();

    // ---------------- phase C: alpha, recurrence, W update ----------------
    if (tid < 32) {
        float nu = num_p[0][tid] + num_p[1][tid];
        float de = den_p[0][tid] + den_p[1][tid];
        alpha_l[tid] = step * (nu / fmaxf(de + regw * nu, 1e-8f));
    }
    __syncthreads();

    int m_l = tid >> 3;
    int mg = m0 + m_l;
    float sa = alpha_l[m_l];

    if (!LAST) {
        int im = mg / 22, jm = mg - im * 22;
#pragma unroll
        for (int ch = 0; ch < 8; ++ch) {
            int col = (tid & 7) * 64 + ch * 8;
            size_t go = ((size_t)(s * 512 + mg)) * 512 + col;
            f16x8 so = *(const f16x8*)(scoresh + go);
            f16x8 sg8 = *(const f16x8*)&Sg[m_l * 512 + col];
            f16x8 sn, rs;
#pragma unroll
            for (int j = 0; j < 8; ++j) {
                float sc = (float)so[j] - sa * (float)sg8[j];
                sn[j] = (_Float16)sc;
                int n = col + j;
                float res = 0.f;
                if (mg < P_ && n < P_) {
                    int kn = n / 22, ln = n - kn * 22;
                    f32x4 m4 = map4t[(kn - im + 21) * 43 + (ln - jm + 21)];
                    float sgn = (sc > 0.f) ? 1.f : ((sc < 0.f) ? -1.f : 0.f);
                    float msk = 0.5f * (1.f - m4[1]) * sgn + 0.5f * (1.f + m4[1]);
                    res = msk * (m4[2] * (msk * sc - m4[0]));
                }
                rs[j] = (_Float16)res;
            }
            *(f16x8*)(scoresh + go) = sn;
            *(f16x8*)(residh + go) = rs;
        }
    }
    if (mg < P_) {
        int cb = (tid & 7) * 32;
        int key = m_l & 15;
        f16x8 wg8[4];
#pragma unroll
        for (int jj = 0; jj < 4; ++jj)
            wg8[jj] = *(const f16x8*)&Wg[m_l * 256 + ((((cb >> 3) + jj) ^ key) << 3)];
#pragma unroll
        for (int q = 0; q < 8; ++q) {
            int c = cb + q * 4;
            size_t o = ((size_t)(s * P_ + mg)) * 256 + c;
            f32x4 wv = *(const f32x4*)(Wf + o);
            f16x4 h;
#pragma unroll
            for (int e = 0; e < 4; ++e) {
                wv[e] -= sa * (float)wg8[q >> 1][(q & 1) * 4 + e];
                h[e] = (_Float16)wv[e];
            }
            *(f32x4*)(Wf + o) = wv;
            if (!LAST) *(f16x4*)(Wh + ((size_t)(s * 512 + mg)) * 256 + c) = h;
        }
    }
}

// ---------------- launch -----------------------------------------------------
extern "C" void kernel_launch(void* const* d_in, const int* in_sizes, int n_in,
                              void* d_out, int out_size, void* d_ws, size_t ws_size,
                              hipStream_t stream) {
    const float* filt = (const float*)d_in[0];
    const float* feat = (const float*)d_in[1];
    const float* lsl  = (const float*)d_in[2];
    const float* freg = (const float*)d_in[3];
    const float* lw   = (const float*)d_in[4];
    const float* mw   = (const float*)d_in[5];
    const float* sw   = (const float*)d_in[6];
    float* Wf = (float*)d_out;

    // workspace carve (bytes)
    char* ws = (char*)d_ws;
    f32x4* map4t     = (f32x4*)ws;      ws += (size_t)TSZ * 16;            // 29.6 KB
    _Float16* residh = (_Float16*)ws;   ws += (size_t)S_ * 512 * 512 * 2;  // 8.4 MB
    _Float16* scoresh= (_Float16*)ws;   ws += (size_t)S_ * 512 * 512 * 2;  // 8.4 MB
    _Float16* Wh     = (_Float16*)ws;   ws += (size_t)S_ * 512 * C_ * 2;   // 4.2 MB
    _Float16* f2h    = (_Float16*)ws;   ws += (size_t)S_ * C_ * 512 * 2;   // 4.2 MB
    _Float16* f2th   = (_Float16*)ws;   ws += (size_t)S_ * 512 * C_ * 2;   // 4.2 MB

    k_pro<<<4112, 256, 0, stream>>>(filt, feat, lw, mw, sw, Wf, Wh, f2h, f2th, map4t);
    k_g1<<<1024, 256, 0, stream>>>(Wh, f2th, map4t, residh, scoresh);
    k_iter<false><<<256, 256, 0, stream>>>(residh, scoresh, f2h, f2th, Wh, Wf, map4t, freg, lsl);
    k_iter<false><<<256, 256, 0, stream>>>(residh, scoresh, f2h, f2th, Wh, Wf, map4t, freg, lsl);
    k_iter<true><<<256, 256, 0, stream>>>(residh, scoresh, f2h, f2th, Wh, Wf, map4t, freg, lsl);
}

// Round 10
// 148.677 us; speedup vs baseline: 1.4692x; 1.4692x over previous
//
#include <hip/hip_runtime.h>
#include <math.h>
#include <stdint.h>

#define Ww 22
#define P_ 484            // H*W (also number of filters)
#define S_ 16
#define C_ 256
#define TSZ 1849          // 43*43 distance table

typedef _Float16 f16x8 __attribute__((ext_vector_type(8)));
typedef _Float16 f16x4 __attribute__((ext_vector_type(4)));
typedef float f32x4 __attribute__((ext_vector_type(4)));

// XCD-chunked remap: grid size n divisible by 8; XCD x (= bid%8) gets wgids
// [x*n/8,(x+1)*n/8) -> each XCD owns the SAME 2 s-slices in every kernel.
__device__ __forceinline__ int xcd_chunk(int bid, int chunk) {
    return (bid & 7) * chunk + (bid >> 3);
}

// ---- global_load_lds width-16: LDS dest is wave-uniform base + lane*16B ----
__device__ __forceinline__ void gld16(const _Float16* g, _Float16* lds) {
    auto* lp = (__attribute__((address_space(3))) uint32_t*)(uintptr_t)(lds);
    auto* gp = (const __attribute__((address_space(1))) uint32_t*)(uintptr_t)(g);
    __builtin_amdgcn_global_load_lds(gp, lp, 16, 0, 0);
}

__device__ __forceinline__ f32x4 map_entry(const float* label_w, const float* mask_w,
                                           const float* spatial_w, float d) {
    float lab = 0.f, msk = 0.f, spw = 0.f;
#pragma unroll
    for (int b = 0; b < 9; ++b) {
        float wb = fmaxf(0.f, 1.f - fabsf(d - (float)b));
        lab += wb * label_w[b];
        msk += wb * mask_w[b];
        spw += wb * spatial_w[b];
    }
    float w9 = fminf(fmaxf(1.f + (d - 9.f), 0.f), 1.f);
    lab += w9 * label_w[9];
    msk += w9 * mask_w[9];
    spw += w9 * spatial_w[9];
    f32x4 o;
    o[0] = lab;
    o[1] = 1.f / (1.f + expf(-msk));
    o[2] = spw * spw;
    o[3] = spw;
    return o;
}

// ---------------- merged prologue: maps + winit + trans ---------------------
__global__ __launch_bounds__(256) void k_pro(
    const float* __restrict__ filt, const float* __restrict__ feat,
    const float* __restrict__ lw, const float* __restrict__ mw,
    const float* __restrict__ sw,
    float* __restrict__ Wf, _Float16* __restrict__ Wh,
    float* __restrict__ num0, float* __restrict__ den0,
    _Float16* __restrict__ f2h, _Float16* __restrict__ f2th,
    f32x4* __restrict__ map4t) {
    int wgid = xcd_chunk(blockIdx.x, 514);
    int x = wgid / 514;
    int local = wgid % 514;
    int t = threadIdx.x;
    if (local == 0) {
        int idx = x + 8 * t;
        if (idx < TSZ) {
            int dx = idx / 43 - 21, dy = idx % 43 - 21;
            float d = sqrtf((float)(dx * dx + dy * dy)) * 2.0f;
            map4t[idx] = map_entry(lw, mw, sw, d);
        }
    } else if (local < 257) {
        int u = local - 1;
        int s = x * 2 + (u >> 7);
        int f = (u & 127) * 4 + (t >> 6);
        int c = (t & 63) * 4;
        size_t oh = ((size_t)(s * 512 + f)) * C_ + c;
        if (f < P_) {
            size_t o = ((size_t)(s * P_ + f)) * C_ + c;
            f32x4 v = *(const f32x4*)(filt + o);
            *(f32x4*)(Wf + o) = v;
            f16x4 h;
#pragma unroll
            for (int q = 0; q < 4; ++q) h[q] = (_Float16)v[q];
            *(f16x4*)(Wh + oh) = h;
            if ((t & 63) == 0) { num0[s * P_ + f] = 0.f; den0[s * P_ + f] = 0.f; }
        } else {
            f16x4 h = {};
            *(f16x4*)(Wh + oh) = h;   // zero pad rows
        }
    } else if (local < 513) {
        int u = local - 257;
        int s = x * 2 + (u >> 7);
        int rem = u & 127;
        int p0 = (rem & 15) * 32, c0 = (rem >> 4) * 32;
        int cc = t & 31, rr = t >> 5;
        __shared__ float tb[32][33];
#pragma unroll
        for (int q = 0; q < 4; ++q) {
            int c = c0 + rr + q * 8;
            int p = p0 + cc;
            float v = (p < P_) ? feat[((size_t)s * C_ + c) * P_ + p] : 0.f;
            f2h[((size_t)s * C_ + c) * 512 + p] = (_Float16)v;
            tb[rr + q * 8][cc] = v;
        }
        __syncthreads();
#pragma unroll
        for (int q = 0; q < 4; ++q) {
            int p = p0 + rr + q * 8;   // rows >= 484 hold zeros
            f2th[((size_t)s * 512 + p) * C_ + c0 + cc] = (_Float16)tb[cc][rr + q * 8];
        }
    }
}

// ---------------- fused MFMA GEMM, T3-minimum 2-phase double-buffer ---------
// 64x64 tiles, 4 waves, BK=128; catalog recipe (m230/m248v2):
//   stage(0); vmcnt(0); barrier;
//   per tile: STAGE(next, cur^1) -> ds_read+MFMA buf[cur] -> vmcnt(0)+barrier
// EPI 1: scores -> scoresh(raw,f16) + residual(f16) + mask(f16)
// EPI 2: wgrad  -> wgradh(f16,+reg*W) + atomic num
// EPI 3: sgrad  -> atomic den (+ optional sgraw write via WSG)
template <int EPI, int KK, int LDA, int LDB, int TPS, int NBN, bool WSG = false>
__global__ __launch_bounds__(256, 2) void k_gemm(
    const _Float16* __restrict__ Ah, const _Float16* __restrict__ Bh,
    const f32x4* __restrict__ map4t, const _Float16* __restrict__ maskh_i,
    const _Float16* __restrict__ Wh_i, const float* __restrict__ freg,
    _Float16* __restrict__ out_h, _Float16* __restrict__ out_h2,
    _Float16* __restrict__ out_h3, float* __restrict__ red) {
    constexpr int TI = 2, TJ = 2, NT = KK / 128;
    int tid = threadIdx.x;
    int w = tid >> 6, l = tid & 63;
    int wgid = xcd_chunk(blockIdx.x, S_ * TPS / 8);
    int s = wgid / TPS;
    int rem = wgid % TPS;
    int m0 = (rem / NBN) * 64, n0 = (rem % NBN) * 64;   // n fastest: share A panel
    int wm = w >> 1, wn = w & 1;
    int r16 = l & 15;

    __shared__ _Float16 As[2][64 * 128];   // 2 x 16 KB
    __shared__ _Float16 Bs[2][64 * 128];   // 2 x 16 KB

    // staging: linear LDS dest (wave-uniform base + lane*16B).
    // invariant: LDS[row][g] = global[row][g ^ (row & 15)]  (16B granules)
    int lrow = w * 4 + (l >> 4);               // row & 15 for every issue
    int gsrc = ((l & 15) ^ lrow) << 3;         // swizzled source granule
    const _Float16* gA = Ah + (size_t)s * (512 * LDA) + (size_t)(m0 + lrow) * LDA + gsrc;
    const _Float16* gB = Bh + (size_t)s * 131072 + (size_t)(n0 + lrow) * LDB + gsrc;

    f32x4 acc[TI][TJ] = {};

    auto stage = [&](int t, int b) {
#pragma unroll
        for (int i = 0; i < 4; ++i) {
            gld16(gA + (size_t)i * 16 * LDA + t * 128, &As[b][(i * 16 + w * 4) * 128]);
            gld16(gB + (size_t)i * 16 * LDB + t * 128, &Bs[b][(i * 16 + w * 4) * 128]);
        }
    };

    // prologue: stage tile 0, drain, barrier
    stage(0, 0);
    asm volatile("s_waitcnt vmcnt(0)" ::: "memory");
    __builtin_amdgcn_s_barrier();

    int cur = 0;
#pragma unroll
    for (int t = 0; t < NT; ++t) {
        if (t + 1 < NT) stage(t + 1, cur ^ 1);   // issue next-tile loads FIRST
        // compute tile t from buf[cur] (regular LDS loads: compiler lgkmcnt)
#pragma unroll
        for (int kk = 0; kk < 4; ++kk) {
            int px = ((kk * 4 + (l >> 4)) ^ r16) << 3;  // read-side XOR swizzle
            f16x8 af[TI], bf[TJ];
#pragma unroll
            for (int ti = 0; ti < TI; ++ti)
                af[ti] = *(const f16x8*)&As[cur][(wm * 32 + ti * 16 + r16) * 128 + px];
#pragma unroll
            for (int tj = 0; tj < TJ; ++tj)
                bf[tj] = *(const f16x8*)&Bs[cur][(wn * 32 + tj * 16 + r16) * 128 + px];
#pragma unroll
            for (int ti = 0; ti < TI; ++ti)
#pragma unroll
                for (int tj = 0; tj < TJ; ++tj)
                    acc[ti][tj] = __builtin_amdgcn_mfma_f32_16x16x32_f16(
                        af[ti], bf[tj], acc[ti][tj], 0, 0, 0);
        }
        // one drain+barrier per tile: prefetch landed, reads of buf[cur] done
        asm volatile("s_waitcnt vmcnt(0)" ::: "memory");
        __builtin_amdgcn_s_barrier();
        cur ^= 1;
    }

    // ---------------- epilogue ----------------
    int q4 = (l >> 4) * 4;

    if constexpr (EPI == 1) {
#pragma unroll
        for (int ti = 0; ti < TI; ++ti)
#pragma unroll
            for (int r = 0; r < 4; ++r) {
                int m = m0 + wm * 32 + ti * 16 + q4 + r;
                int im = m / 22, jm = m - im * 22;
#pragma unroll
                for (int tj = 0; tj < TJ; ++tj) {
                    int n = n0 + wn * 32 + tj * 16 + r16;
                    float sc = acc[ti][tj][r];     // pads -> 0 (zero operands)
                    float res = 0.f;
                    size_t po = ((size_t)(s * 512 + m)) * 512 + n;
                    if (m < P_ && n < P_) {
                        int kn = n / 22, ln = n - kn * 22;
                        f32x4 m4 = map4t[(kn - im + 21) * 43 + (ln - jm + 21)];
                        float sgn = (sc > 0.f) ? 1.f : ((sc < 0.f) ? -1.f : 0.f);
                        float msk = 0.5f * (1.f - m4[1]) * sgn + 0.5f * (1.f + m4[1]);
                        res = msk * (m4[2] * (msk * sc - m4[0]));
                        out_h2[po] = (_Float16)msk;
                    }
                    out_h[po] = (_Float16)res;     // residh (pads -> 0)
                    out_h3[po] = (_Float16)sc;     // scoresh (pads -> 0)
                }
            }
    } else if constexpr (EPI == 2) {
        float fr = freg[0];
        float regw = fmaxf(fr * fr, 1e-10f);
#pragma unroll
        for (int ti = 0; ti < TI; ++ti)
#pragma unroll
            for (int r = 0; r < 4; ++r) {
                int m = m0 + wm * 32 + ti * 16 + q4 + r;
                float v = 0.f;
#pragma unroll
                for (int tj = 0; tj < TJ; ++tj) {
                    int n = n0 + wn * 32 + tj * 16 + r16;   // n < 256 always
                    size_t o = ((size_t)(s * 512 + m)) * C_ + n;
                    // pad rows: acc==0 and Wh==0 -> wg==0 (wgradh pads stay 0)
                    float wg = acc[ti][tj][r] + regw * (float)Wh_i[o];
                    out_h[o] = (_Float16)wg;
                    v += wg * wg;
                }
                v += __shfl_xor(v, 1);
                v += __shfl_xor(v, 2);
                v += __shfl_xor(v, 4);
                v += __shfl_xor(v, 8);
                if (r16 == 0 && m < P_) atomicAdd(&red[s * P_ + m], v);
            }
    } else {
#pragma unroll
        for (int ti = 0; ti < TI; ++ti)
#pragma unroll
            for (int r = 0; r < 4; ++r) {
                int m = m0 + wm * 32 + ti * 16 + q4 + r;
                int im = m / 22, jm = m - im * 22;
                float v = 0.f;
#pragma unroll
                for (int tj = 0; tj < TJ; ++tj) {
                    int n = n0 + wn * 32 + tj * 16 + r16;
                    float sc = acc[ti][tj][r];
                    if constexpr (WSG)
                        out_h[((size_t)(s * 512 + m)) * 512 + n] = (_Float16)sc;  // sgraw
                    if (m < P_ && n < P_) {
                        int kn = n / 22, ln = n - kn * 22;
                        float spw = map4t[(kn - im + 21) * 43 + (ln - jm + 21)][3];
                        float msk = (float)maskh_i[((size_t)(s * 512 + m)) * 512 + n];
                        float sg = spw * msk * sc;
                        v += sg * sg;
                    }
                }
                v += __shfl_xor(v, 1);
                v += __shfl_xor(v, 2);
                v += __shfl_xor(v, 4);
                v += __shfl_xor(v, 8);
                if (r16 == 0 && m < P_) atomicAdd(&red[s * P_ + m], v);
            }
    }
}

// ---------------- fused: W-update + scores recurrence + residual epilogue ---
__global__ __launch_bounds__(256) void k_fu(
    float* __restrict__ Wf, _Float16* __restrict__ Wh,
    const _Float16* __restrict__ wgradh,
    const float* __restrict__ num_rd, const float* __restrict__ den_rd,
    float* __restrict__ num_zw, float* __restrict__ den_zw,
    const _Float16* __restrict__ sgrawh, _Float16* __restrict__ scoresh,
    _Float16* __restrict__ residh, _Float16* __restrict__ maskh,
    const f32x4* __restrict__ map4t,
    const float* __restrict__ freg, const float* __restrict__ lsl) {
    int wgid = xcd_chunk(blockIdx.x, 484);
    int s = wgid / 242;
    int local = wgid % 242;
    int t = threadIdx.x;
    float fr = freg[0];
    float regw = fmaxf(fr * fr, 1e-10f);
    float step = expf(lsl[0]);
    if (local < 121) {
        int f = local * 4 + (t >> 6);
        int row = s * P_ + f;
        float nu = num_rd[row], de = den_rd[row];
        float sa = step * (nu / fmaxf(de + regw * nu, 1e-8f));
        int c = (t & 63) * 4;
        size_t o = (size_t)row * C_ + c;
        size_t oh = ((size_t)(s * 512 + f)) * C_ + c;
        f32x4 wv = *(const f32x4*)(Wf + o);
        f16x4 g = *(const f16x4*)(wgradh + oh);
        f16x4 h;
#pragma unroll
        for (int q = 0; q < 4; ++q) {
            wv[q] -= sa * (float)g[q];
            h[q] = (_Float16)wv[q];
        }
        *(f32x4*)(Wf + o) = wv;
        *(f16x4*)(Wh + oh) = h;
        if ((t & 63) == 0) { num_zw[row] = 0.f; den_zw[row] = 0.f; }
    } else {
        int m = (local - 121) * 4 + (t >> 6);   // < 484
        int row = s * P_ + m;
        float nu = num_rd[row], de = den_rd[row];
        float sa = step * (nu / fmaxf(de + regw * nu, 1e-8f));
        int im = m / 22, jm = m - im * 22;
        int n0 = (t & 63) * 8;
        size_t ro = ((size_t)(s * 512 + m)) * 512 + n0;
        f16x8 so = *(const f16x8*)(scoresh + ro);
        f16x8 gg = *(const f16x8*)(sgrawh + ro);
        f16x8 sn, rs, mk;
#pragma unroll
        for (int j = 0; j < 8; ++j) {
            float sc = (float)so[j] - sa * (float)gg[j];
            sn[j] = (_Float16)sc;
            int n = n0 + j;
            float res = 0.f, msk = 0.f;
            if (n < P_) {
                int kn = n / 22, ln = n - kn * 22;
                f32x4 m4 = map4t[(kn - im + 21) * 43 + (ln - jm + 21)];
                float sgn = (sc > 0.f) ? 1.f : ((sc < 0.f) ? -1.f : 0.f);
                msk = 0.5f * (1.f - m4[1]) * sgn + 0.5f * (1.f + m4[1]);
                res = msk * (m4[2] * (msk * sc - m4[0]));
            }
            rs[j] = (_Float16)res;
            mk[j] = (_Float16)msk;
        }
        *(f16x8*)(scoresh + ro) = sn;
        *(f16x8*)(residh + ro) = rs;
        *(f16x8*)(maskh + ro) = mk;
    }
}

// ---------------- final update: alpha + w step ------------------------------
__global__ __launch_bounds__(256) void k_update(float* __restrict__ Wf,
                                                const _Float16* __restrict__ wgradh,
                                                const float* __restrict__ num,
                                                const float* __restrict__ den,
                                                const float* __restrict__ freg,
                                                const float* __restrict__ lsl) {
    int wgid = xcd_chunk(blockIdx.x, 242);
    int s = wgid / 121;
    int t = threadIdx.x;
    int f = (wgid % 121) * 4 + (t >> 6);
    int row = s * P_ + f;
    float nu = num[row], de = den[row];
    float fr = freg[0];
    float regw = fmaxf(fr * fr, 1e-10f);
    float sa = expf(lsl[0]) * (nu / fmaxf(de + regw * nu, 1e-8f));
    int c = (t & 63) * 4;
    size_t o = (size_t)row * C_ + c;
    size_t oh = ((size_t)(s * 512 + f)) * C_ + c;
    f32x4 wv = *(const f32x4*)(Wf + o);
    f16x4 g = *(const f16x4*)(wgradh + oh);
#pragma unroll
    for (int q = 0; q < 4; ++q) wv[q] -= sa * (float)g[q];
    *(f32x4*)(Wf + o) = wv;
}

// ---------------- launch -----------------------------------------------------
extern "C" void kernel_launch(void* const* d_in, const int* in_sizes, int n_in,
                              void* d_out, int out_size, void* d_ws, size_t ws_size,
                              hipStream_t stream) {
    const float* filt = (const float*)d_in[0];
    const float* feat = (const float*)d_in[1];
    const float* lsl  = (const float*)d_in[2];
    const float* freg = (const float*)d_in[3];
    const float* lw   = (const float*)d_in[4];
    const float* mw   = (const float*)d_in[5];
    const float* sw   = (const float*)d_in[6];
    float* Wf = (float*)d_out;

    // workspace carve (bytes)
    char* ws = (char*)d_ws;
    f32x4* map4t     = (f32x4*)ws;      ws += (size_t)TSZ * 16;            // 29.6 KB
    _Float16* residh = (_Float16*)ws;   ws += (size_t)S_ * 512 * 512 * 2;  // 8.4 MB
    _Float16* scoresh= (_Float16*)ws;   ws += (size_t)S_ * 512 * 512 * 2;  // 8.4 MB
    _Float16* sgrawh = (_Float16*)ws;   ws += (size_t)S_ * 512 * 512 * 2;  // 8.4 MB
    _Float16* maskh  = (_Float16*)ws;   ws += (size_t)S_ * 512 * 512 * 2;  // 8.4 MB
    _Float16* wgradh = (_Float16*)ws;   ws += (size_t)S_ * 512 * C_ * 2;   // 4.2 MB
    _Float16* Wh     = (_Float16*)ws;   ws += (size_t)S_ * 512 * C_ * 2;   // 4.2 MB
    _Float16* f2h    = (_Float16*)ws;   ws += (size_t)S_ * C_ * 512 * 2;   // 4.2 MB
    _Float16* f2th   = (_Float16*)ws;   ws += (size_t)S_ * 512 * C_ * 2;   // 4.2 MB
    float* num0      = (float*)ws;      ws += (size_t)S_ * P_ * 4;
    float* den0      = (float*)ws;      ws += (size_t)S_ * P_ * 4;
    float* num1      = (float*)ws;      ws += (size_t)S_ * P_ * 4;
    float* den1      = (float*)ws;      ws += (size_t)S_ * P_ * 4;

    // prologue: maps + winit (zeroes bank0) + trans
    k_pro<<<4112, 256, 0, stream>>>(filt, feat, lw, mw, sw, Wf, Wh, num0, den0,
                                    f2h, f2th, map4t);

    // ---- iteration 0 ----
    k_gemm<1, 256, 256, 256, 64, 8><<<1024, 256, 0, stream>>>(
        Wh, f2th, map4t, nullptr, nullptr, nullptr, residh, maskh, scoresh, nullptr);
    k_gemm<2, 512, 512, 512, 32, 4><<<512, 256, 0, stream>>>(
        residh, f2h, map4t, nullptr, Wh, freg, wgradh, nullptr, nullptr, num0);
    k_gemm<3, 256, 256, 256, 64, 8, true><<<1024, 256, 0, stream>>>(
        wgradh, f2th, map4t, maskh, nullptr, nullptr, sgrawh, nullptr, nullptr, den0);
    // ---- iteration 1 ----
    k_fu<<<3872, 256, 0, stream>>>(Wf, Wh, wgradh, num0, den0, num1, den1,
                                   sgrawh, scoresh, residh, maskh, map4t, freg, lsl);
    k_gemm<2, 512, 512, 512, 32, 4><<<512, 256, 0, stream>>>(
        residh, f2h, map4t, nullptr, Wh, freg, wgradh, nullptr, nullptr, num1);
    k_gemm<3, 256, 256, 256, 64, 8, true><<<1024, 256, 0, stream>>>(
        wgradh, f2th, map4t, maskh, nullptr, nullptr, sgrawh, nullptr, nullptr, den1);
    // ---- iteration 2 ----
    k_fu<<<3872, 256, 0, stream>>>(Wf, Wh, wgradh, num1, den1, num0, den0,
                                   sgrawh, scoresh, residh, maskh, map4t, freg, lsl);
    k_gemm<2, 512, 512, 512, 32, 4><<<512, 256, 0, stream>>>(
        residh, f2h, map4t, nullptr, Wh, freg, wgradh, nullptr, nullptr, num0);
    k_gemm<3, 256, 256, 256, 64, 8, false><<<1024, 256, 0, stream>>>(
        wgradh, f2th, map4t, maskh, nullptr, nullptr, nullptr, nullptr, nullptr, den0);
    // ---- final W step ----
    k_update<<<1936, 256, 0, stream>>>(Wf, wgradh, num0, den0, freg, lsl);
}

// Round 11
// 127.199 us; speedup vs baseline: 1.7172x; 1.1688x over previous
//
#include <hip/hip_runtime.h>
#include <math.h>
#include <stdint.h>

#define Ww 22
#define P_ 484            // H*W (also number of filters)
#define S_ 16
#define C_ 256
#define TSZ 1849          // 43*43 distance table

typedef _Float16 f16x8 __attribute__((ext_vector_type(8)));
typedef _Float16 f16x4 __attribute__((ext_vector_type(4)));
typedef float f32x4 __attribute__((ext_vector_type(4)));

// XCD-chunked remap: grid size n divisible by 8; XCD x (= bid%8) gets wgids
// [x*n/8,(x+1)*n/8) -> each XCD owns the SAME 2 s-slices in every kernel.
__device__ __forceinline__ int xcd_chunk(int bid, int chunk) {
    return (bid & 7) * chunk + (bid >> 3);
}

// ---- global_load_lds width-16: LDS dest is wave-uniform base + lane*16B ----
__device__ __forceinline__ void gld16(const _Float16* g, _Float16* lds) {
    auto* lp = (__attribute__((address_space(3))) uint32_t*)(uintptr_t)(lds);
    auto* gp = (const __attribute__((address_space(1))) uint32_t*)(uintptr_t)(g);
    __builtin_amdgcn_global_load_lds(gp, lp, 16, 0, 0);
}

__device__ __forceinline__ f32x4 map_entry(const float* label_w, const float* mask_w,
                                           const float* spatial_w, float d) {
    float lab = 0.f, msk = 0.f, spw = 0.f;
#pragma unroll
    for (int b = 0; b < 9; ++b) {
        float wb = fmaxf(0.f, 1.f - fabsf(d - (float)b));
        lab += wb * label_w[b];
        msk += wb * mask_w[b];
        spw += wb * spatial_w[b];
    }
    float w9 = fminf(fmaxf(1.f + (d - 9.f), 0.f), 1.f);
    lab += w9 * label_w[9];
    msk += w9 * mask_w[9];
    spw += w9 * spatial_w[9];
    f32x4 o;
    o[0] = lab;
    o[1] = 1.f / (1.f + expf(-msk));
    o[2] = spw * spw;
    o[3] = spw;
    return o;
}

// ---------------- merged prologue: maps + winit + trans ---------------------
__global__ __launch_bounds__(256) void k_pro(
    const float* __restrict__ filt, const float* __restrict__ feat,
    const float* __restrict__ lw, const float* __restrict__ mw,
    const float* __restrict__ sw,
    float* __restrict__ Wf, _Float16* __restrict__ Wh,
    float* __restrict__ num0, float* __restrict__ den0,
    _Float16* __restrict__ f2h, _Float16* __restrict__ f2th,
    f32x4* __restrict__ map4t) {
    int wgid = xcd_chunk(blockIdx.x, 514);
    int x = wgid / 514;
    int local = wgid % 514;
    int t = threadIdx.x;
    if (local == 0) {
        int idx = x + 8 * t;
        if (idx < TSZ) {
            int dx = idx / 43 - 21, dy = idx % 43 - 21;
            float d = sqrtf((float)(dx * dx + dy * dy)) * 2.0f;
            map4t[idx] = map_entry(lw, mw, sw, d);
        }
    } else if (local < 257) {
        int u = local - 1;
        int s = x * 2 + (u >> 7);
        int f = (u & 127) * 4 + (t >> 6);
        int c = (t & 63) * 4;
        size_t oh = ((size_t)(s * 512 + f)) * C_ + c;
        if (f < P_) {
            size_t o = ((size_t)(s * P_ + f)) * C_ + c;
            f32x4 v = *(const f32x4*)(filt + o);
            *(f32x4*)(Wf + o) = v;
            f16x4 h;
#pragma unroll
            for (int q = 0; q < 4; ++q) h[q] = (_Float16)v[q];
            *(f16x4*)(Wh + oh) = h;
            if ((t & 63) == 0) { num0[s * P_ + f] = 0.f; den0[s * P_ + f] = 0.f; }
        } else {
            f16x4 h = {};
            *(f16x4*)(Wh + oh) = h;   // zero pad rows
        }
    } else if (local < 513) {
        int u = local - 257;
        int s = x * 2 + (u >> 7);
        int rem = u & 127;
        int p0 = (rem & 15) * 32, c0 = (rem >> 4) * 32;
        int cc = t & 31, rr = t >> 5;
        __shared__ float tb[32][33];
#pragma unroll
        for (int q = 0; q < 4; ++q) {
            int c = c0 + rr + q * 8;
            int p = p0 + cc;
            float v = (p < P_) ? feat[((size_t)s * C_ + c) * P_ + p] : 0.f;
            f2h[((size_t)s * C_ + c) * 512 + p] = (_Float16)v;
            tb[rr + q * 8][cc] = v;
        }
        __syncthreads();
#pragma unroll
        for (int q = 0; q < 4; ++q) {
            int p = p0 + rr + q * 8;   // rows >= 484 hold zeros
            f2th[((size_t)s * 512 + p) * C_ + c0 + cc] = (_Float16)tb[cc][rr + q * 8];
        }
    }
}

// ---------------- fused MFMA GEMM, single-buffer LDS (round-8-proven loop) --
// BM x 64 tiles, 4 waves, BK=128; stage -> sync -> compute -> sync.
// EPI 1 (BM=64): scores -> scoresh(raw,f16) + residual(f16)
// EPI 2 (BM=32): wgrad  -> wgradh(f16,+reg*W) + atomic num
// EPI 3 (BM=64): sgrad  -> atomic den, mask recomputed from scoresh
//                (+ optional sgraw write via WSG)
template <int EPI, int BM, int KK, int LDA, int LDB, int TPS, int NBN, bool WSG = false>
__global__ __launch_bounds__(256, 4) void k_gemm(
    const _Float16* __restrict__ Ah, const _Float16* __restrict__ Bh,
    const f32x4* __restrict__ map4t, const _Float16* __restrict__ sch_i,
    const _Float16* __restrict__ Wh_i, const float* __restrict__ freg,
    _Float16* __restrict__ out_h, _Float16* __restrict__ out_h3,
    float* __restrict__ red) {
    constexpr int TI = BM / 32, TJ = 2, NT = KK / 128, NIA = BM / 16;
    int tid = threadIdx.x;
    int w = tid >> 6, l = tid & 63;
    int wgid = xcd_chunk(blockIdx.x, S_ * TPS / 8);
    int s = wgid / TPS;
    int rem = wgid % TPS;
    int m0 = (rem / NBN) * BM, n0 = (rem % NBN) * 64;   // n fastest: share A panel
    int wm = w >> 1, wn = w & 1;
    int r16 = l & 15;

    __shared__ _Float16 As[BM * 128];
    __shared__ _Float16 Bs[64 * 128];

    // staging: linear LDS dest (wave-uniform base + lane*16B).
    // invariant: LDS[row][g] = global[row][g ^ (row & 15)]  (16B granules)
    int lrow = w * 4 + (l >> 4);               // row & 15 for every issue
    int gsrc = ((l & 15) ^ lrow) << 3;         // swizzled source granule
    const _Float16* gA = Ah + (size_t)s * (512 * LDA) + (size_t)(m0 + lrow) * LDA + gsrc;
    const _Float16* gB = Bh + (size_t)s * 131072 + (size_t)(n0 + lrow) * LDB + gsrc;

    f32x4 acc[TI][TJ] = {};

#pragma unroll
    for (int t = 0; t < NT; ++t) {
        // ---- stage K-chunk t (128 wide) ----
#pragma unroll
        for (int i = 0; i < NIA; ++i)
            gld16(gA + (size_t)i * 16 * LDA + t * 128, &As[(i * 16 + w * 4) * 128]);
#pragma unroll
        for (int i = 0; i < 4; ++i)
            gld16(gB + (size_t)i * 16 * LDB + t * 128, &Bs[(i * 16 + w * 4) * 128]);
        __syncthreads();   // drain vmcnt -> staged data visible to all waves
        // ---- compute: 4 MFMA k-slices of 32 ----
#pragma unroll
        for (int kk = 0; kk < 4; ++kk) {
            int px = ((kk * 4 + (l >> 4)) ^ r16) << 3;  // read-side XOR swizzle
            f16x8 af[TI], bf[TJ];
#pragma unroll
            for (int ti = 0; ti < TI; ++ti)
                af[ti] = *(const f16x8*)&As[(wm * (BM / 2) + ti * 16 + r16) * 128 + px];
#pragma unroll
            for (int tj = 0; tj < TJ; ++tj)
                bf[tj] = *(const f16x8*)&Bs[(wn * 32 + tj * 16 + r16) * 128 + px];
#pragma unroll
            for (int ti = 0; ti < TI; ++ti)
#pragma unroll
                for (int tj = 0; tj < TJ; ++tj)
                    acc[ti][tj] = __builtin_amdgcn_mfma_f32_16x16x32_f16(
                        af[ti], bf[tj], acc[ti][tj], 0, 0, 0);
        }
        if (t + 1 < NT) __syncthreads();   // protect LDS reuse
    }

    // ---------------- epilogue ----------------
    int q4 = (l >> 4) * 4;

    if constexpr (EPI == 1) {
#pragma unroll
        for (int ti = 0; ti < TI; ++ti)
#pragma unroll
            for (int r = 0; r < 4; ++r) {
                int m = m0 + wm * (BM / 2) + ti * 16 + q4 + r;
                int im = m / 22, jm = m - im * 22;
#pragma unroll
                for (int tj = 0; tj < TJ; ++tj) {
                    int n = n0 + wn * 32 + tj * 16 + r16;
                    float sc = acc[ti][tj][r];     // pads -> 0 (zero operands)
                    float res = 0.f;
                    size_t po = ((size_t)(s * 512 + m)) * 512 + n;
                    if (m < P_ && n < P_) {
                        int kn = n / 22, ln = n - kn * 22;
                        f32x4 m4 = map4t[(kn - im + 21) * 43 + (ln - jm + 21)];
                        float sgn = (sc > 0.f) ? 1.f : ((sc < 0.f) ? -1.f : 0.f);
                        float msk = 0.5f * (1.f - m4[1]) * sgn + 0.5f * (1.f + m4[1]);
                        res = msk * (m4[2] * (msk * sc - m4[0]));
                    }
                    out_h[po] = (_Float16)res;     // residh (pads -> 0)
                    out_h3[po] = (_Float16)sc;     // scoresh (pads -> 0)
                }
            }
    } else if constexpr (EPI == 2) {
        float fr = freg[0];
        float regw = fmaxf(fr * fr, 1e-10f);
#pragma unroll
        for (int ti = 0; ti < TI; ++ti)
#pragma unroll
            for (int r = 0; r < 4; ++r) {
                int m = m0 + wm * (BM / 2) + ti * 16 + q4 + r;
                float v = 0.f;
#pragma unroll
                for (int tj = 0; tj < TJ; ++tj) {
                    int n = n0 + wn * 32 + tj * 16 + r16;   // n < 256 always
                    size_t o = ((size_t)(s * 512 + m)) * C_ + n;
                    // pad rows: acc==0 and Wh==0 -> wg==0 (wgradh pads stay 0)
                    float wg = acc[ti][tj][r] + regw * (float)Wh_i[o];
                    out_h[o] = (_Float16)wg;
                    v += wg * wg;
                }
                v += __shfl_xor(v, 1);
                v += __shfl_xor(v, 2);
                v += __shfl_xor(v, 4);
                v += __shfl_xor(v, 8);
                if (r16 == 0 && m < P_) atomicAdd(&red[s * P_ + m], v);
            }
    } else {
#pragma unroll
        for (int ti = 0; ti < TI; ++ti)
#pragma unroll
            for (int r = 0; r < 4; ++r) {
                int m = m0 + wm * (BM / 2) + ti * 16 + q4 + r;
                int im = m / 22, jm = m - im * 22;
                float v = 0.f;
#pragma unroll
                for (int tj = 0; tj < TJ; ++tj) {
                    int n = n0 + wn * 32 + tj * 16 + r16;
                    float a = acc[ti][tj][r];
                    size_t po = ((size_t)(s * 512 + m)) * 512 + n;
                    if constexpr (WSG) out_h[po] = (_Float16)a;   // sgraw
                    if (m < P_ && n < P_) {
                        int kn = n / 22, ln = n - kn * 22;
                        f32x4 m4 = map4t[(kn - im + 21) * 43 + (ln - jm + 21)];
                        float sc = (float)sch_i[po];
                        float sgn = (sc > 0.f) ? 1.f : ((sc < 0.f) ? -1.f : 0.f);
                        float msk = 0.5f * (1.f - m4[1]) * sgn + 0.5f * (1.f + m4[1]);
                        float sg = m4[3] * msk * a;
                        v += sg * sg;
                    }
                }
                v += __shfl_xor(v, 1);
                v += __shfl_xor(v, 2);
                v += __shfl_xor(v, 4);
                v += __shfl_xor(v, 8);
                if (r16 == 0 && m < P_) atomicAdd(&red[s * P_ + m], v);
            }
    }
}

// ---------------- fused: W-update + scores recurrence + residual epilogue ---
__global__ __launch_bounds__(256) void k_fu(
    float* __restrict__ Wf, _Float16* __restrict__ Wh,
    const _Float16* __restrict__ wgradh,
    const float* __restrict__ num_rd, const float* __restrict__ den_rd,
    float* __restrict__ num_zw, float* __restrict__ den_zw,
    const _Float16* __restrict__ sgrawh, _Float16* __restrict__ scoresh,
    _Float16* __restrict__ residh,
    const f32x4* __restrict__ map4t,
    const float* __restrict__ freg, const float* __restrict__ lsl) {
    int wgid = xcd_chunk(blockIdx.x, 484);
    int s = wgid / 242;
    int local = wgid % 242;
    int t = threadIdx.x;
    float fr = freg[0];
    float regw = fmaxf(fr * fr, 1e-10f);
    float step = expf(lsl[0]);
    if (local < 121) {
        int f = local * 4 + (t >> 6);
        int row = s * P_ + f;
        float nu = num_rd[row], de = den_rd[row];
        float sa = step * (nu / fmaxf(de + regw * nu, 1e-8f));
        int c = (t & 63) * 4;
        size_t o = (size_t)row * C_ + c;
        size_t oh = ((size_t)(s * 512 + f)) * C_ + c;
        f32x4 wv = *(const f32x4*)(Wf + o);
        f16x4 g = *(const f16x4*)(wgradh + oh);
        f16x4 h;
#pragma unroll
        for (int q = 0; q < 4; ++q) {
            wv[q] -= sa * (float)g[q];
            h[q] = (_Float16)wv[q];
        }
        *(f32x4*)(Wf + o) = wv;
        *(f16x4*)(Wh + oh) = h;
        if ((t & 63) == 0) { num_zw[row] = 0.f; den_zw[row] = 0.f; }
    } else {
        int m = (local - 121) * 4 + (t >> 6);   // < 484
        int row = s * P_ + m;
        float nu = num_rd[row], de = den_rd[row];
        float sa = step * (nu / fmaxf(de + regw * nu, 1e-8f));
        int im = m / 22, jm = m - im * 22;
        int n0 = (t & 63) * 8;
        size_t ro = ((size_t)(s * 512 + m)) * 512 + n0;
        f16x8 so = *(const f16x8*)(scoresh + ro);
        f16x8 gg = *(const f16x8*)(sgrawh + ro);
        f16x8 sn, rs;
#pragma unroll
        for (int j = 0; j < 8; ++j) {
            float sc = (float)so[j] - sa * (float)gg[j];
            sn[j] = (_Float16)sc;
            int n = n0 + j;
            float res = 0.f;
            if (n < P_) {
                int kn = n / 22, ln = n - kn * 22;
                f32x4 m4 = map4t[(kn - im + 21) * 43 + (ln - jm + 21)];
                float sgn = (sc > 0.f) ? 1.f : ((sc < 0.f) ? -1.f : 0.f);
                float msk = 0.5f * (1.f - m4[1]) * sgn + 0.5f * (1.f + m4[1]);
                res = msk * (m4[2] * (msk * sc - m4[0]));
            }
            rs[j] = (_Float16)res;
        }
        *(f16x8*)(scoresh + ro) = sn;
        *(f16x8*)(residh + ro) = rs;
    }
}

// ---------------- final update: alpha + w step ------------------------------
__global__ __launch_bounds__(256) void k_update(float* __restrict__ Wf,
                                                const _Float16* __restrict__ wgradh,
                                                const float* __restrict__ num,
                                                const float* __restrict__ den,
                                                const float* __restrict__ freg,
                                                const float* __restrict__ lsl) {
    int wgid = xcd_chunk(blockIdx.x, 242);
    int s = wgid / 121;
    int t = threadIdx.x;
    int f = (wgid % 121) * 4 + (t >> 6);
    int row = s * P_ + f;
    float nu = num[row], de = den[row];
    float fr = freg[0];
    float regw = fmaxf(fr * fr, 1e-10f);
    float sa = expf(lsl[0]) * (nu / fmaxf(de + regw * nu, 1e-8f));
    int c = (t & 63) * 4;
    size_t o = (size_t)row * C_ + c;
    size_t oh = ((size_t)(s * 512 + f)) * C_ + c;
    f32x4 wv = *(const f32x4*)(Wf + o);
    f16x4 g = *(const f16x4*)(wgradh + oh);
#pragma unroll
    for (int q = 0; q < 4; ++q) wv[q] -= sa * (float)g[q];
    *(f32x4*)(Wf + o) = wv;
}

// ---------------- launch -----------------------------------------------------
extern "C" void kernel_launch(void* const* d_in, const int* in_sizes, int n_in,
                              void* d_out, int out_size, void* d_ws, size_t ws_size,
                              hipStream_t stream) {
    const float* filt = (const float*)d_in[0];
    const float* feat = (const float*)d_in[1];
    const float* lsl  = (const float*)d_in[2];
    const float* freg = (const float*)d_in[3];
    const float* lw   = (const float*)d_in[4];
    const float* mw   = (const float*)d_in[5];
    const float* sw   = (const float*)d_in[6];
    float* Wf = (float*)d_out;

    // workspace carve (bytes)
    char* ws = (char*)d_ws;
    f32x4* map4t     = (f32x4*)ws;      ws += (size_t)TSZ * 16;            // 29.6 KB
    _Float16* residh = (_Float16*)ws;   ws += (size_t)S_ * 512 * 512 * 2;  // 8.4 MB
    _Float16* scoresh= (_Float16*)ws;   ws += (size_t)S_ * 512 * 512 * 2;  // 8.4 MB
    _Float16* sgrawh = (_Float16*)ws;   ws += (size_t)S_ * 512 * 512 * 2;  // 8.4 MB
    _Float16* wgradh = (_Float16*)ws;   ws += (size_t)S_ * 512 * C_ * 2;   // 4.2 MB
    _Float16* Wh     = (_Float16*)ws;   ws += (size_t)S_ * 512 * C_ * 2;   // 4.2 MB
    _Float16* f2h    = (_Float16*)ws;   ws += (size_t)S_ * C_ * 512 * 2;   // 4.2 MB
    _Float16* f2th   = (_Float16*)ws;   ws += (size_t)S_ * 512 * C_ * 2;   // 4.2 MB
    float* num0      = (float*)ws;      ws += (size_t)S_ * P_ * 4;
    float* den0      = (float*)ws;      ws += (size_t)S_ * P_ * 4;
    float* num1      = (float*)ws;      ws += (size_t)S_ * P_ * 4;
    float* den1      = (float*)ws;      ws += (size_t)S_ * P_ * 4;

    // prologue: maps + winit (zeroes bank0) + trans
    k_pro<<<4112, 256, 0, stream>>>(filt, feat, lw, mw, sw, Wf, Wh, num0, den0,
                                    f2h, f2th, map4t);

    // ---- iteration 0 ----
    k_gemm<1, 64, 256, 256, 256, 64, 8><<<1024, 256, 0, stream>>>(
        Wh, f2th, map4t, nullptr, nullptr, nullptr, residh, scoresh, nullptr);
    k_gemm<2, 32, 512, 512, 512, 64, 4><<<1024, 256, 0, stream>>>(
        residh, f2h, map4t, nullptr, Wh, freg, wgradh, nullptr, num0);
    k_gemm<3, 64, 256, 256, 256, 64, 8, true><<<1024, 256, 0, stream>>>(
        wgradh, f2th, map4t, scoresh, nullptr, nullptr, sgrawh, nullptr, den0);
    // ---- iteration 1 ----
    k_fu<<<3872, 256, 0, stream>>>(Wf, Wh, wgradh, num0, den0, num1, den1,
                                   sgrawh, scoresh, residh, map4t, freg, lsl);
    k_gemm<2, 32, 512, 512, 512, 64, 4><<<1024, 256, 0, stream>>>(
        residh, f2h, map4t, nullptr, Wh, freg, wgradh, nullptr, num1);
    k_gemm<3, 64, 256, 256, 256, 64, 8, true><<<1024, 256, 0, stream>>>(
        wgradh, f2th, map4t, scoresh, nullptr, nullptr, sgrawh, nullptr, den1);
    // ---- iteration 2 ----
    k_fu<<<3872, 256, 0, stream>>>(Wf, Wh, wgradh, num1, den1, num0, den0,
                                   sgrawh, scoresh, residh, map4t, freg, lsl);
    k_gemm<2, 32, 512, 512, 512, 64, 4><<<1024, 256, 0, stream>>>(
        residh, f2h, map4t, nullptr, Wh, freg, wgradh, nullptr, num0);
    k_gemm<3, 64, 256, 256, 256, 64, 8, false><<<1024, 256, 0, stream>>>(
        wgradh, f2th, map4t, scoresh, nullptr, nullptr, nullptr, nullptr, den0);
    // ---- final W step ----
    k_update<<<1936, 256, 0, stream>>>(Wf, wgradh, num0, den0, freg, lsl);
}